// Round 1
// baseline (347.524 us; speedup 1.0000x reference)
//
#include <hip/hip_runtime.h>
#include <math.h>

#define N_NODES 50000
#define N_EDGES 800000
#define IN_F 128
#define OUT_F 64
#define E_TOT (N_EDGES + N_NODES)
#define NEG_SLOPE 0.2f
#define GEMM_ROWS 4

// Monotonic float<->uint encoding so float-max can use atomicMax(unsigned).
__device__ __forceinline__ unsigned enc_f32(float f) {
    unsigned u = __float_as_uint(f);
    return (u & 0x80000000u) ? ~u : (u | 0x80000000u);
}
__device__ __forceinline__ float dec_f32(unsigned u) {
    unsigned b = (u & 0x80000000u) ? (u & 0x7FFFFFFFu) : ~u;
    return __uint_as_float(b);
}
#define ENC_NEG_INF 0x007FFFFFu  // enc_f32(-inf)

__global__ void k_init(float* __restrict__ out, float* __restrict__ denom,
                       unsigned* __restrict__ emax) {
    int i = blockIdx.x * blockDim.x + threadIdx.x;
    if (i < N_NODES * OUT_F) {
        out[i] = 0.f;
        if (i < N_NODES) { denom[i] = 0.f; emax[i] = ENC_NEG_INF; }
    }
}

// h = x @ W  (one wave per GEMM_ROWS rows, lane = output channel)
// plus fused a_src = h@att_src, a_dst = h@att_dst via wave shuffle reduce.
__global__ __launch_bounds__(256) void k_gemm(
    const float* __restrict__ x, const float* __restrict__ W,
    const float* __restrict__ att_src, const float* __restrict__ att_dst,
    float* __restrict__ h, float* __restrict__ a_src, float* __restrict__ a_dst) {
    __shared__ float Wl[IN_F * OUT_F];  // 32 KB
    int tid = threadIdx.x;
    for (int i = tid; i < IN_F * OUT_F; i += 256) Wl[i] = W[i];
    __syncthreads();

    int wave = tid >> 6;
    int lane = tid & 63;
    float as = att_src[lane];
    float ad = att_dst[lane];

    int row0 = (blockIdx.x * 4 + wave) * GEMM_ROWS;
    if (row0 >= N_NODES) return;
    int nr = min(GEMM_ROWS, N_NODES - row0);

    float acc[GEMM_ROWS] = {0.f, 0.f, 0.f, 0.f};
    for (int k0 = 0; k0 < IN_F; k0 += 4) {
        float w0 = Wl[(k0 + 0) * OUT_F + lane];
        float w1 = Wl[(k0 + 1) * OUT_F + lane];
        float w2 = Wl[(k0 + 2) * OUT_F + lane];
        float w3 = Wl[(k0 + 3) * OUT_F + lane];
#pragma unroll
        for (int r = 0; r < GEMM_ROWS; ++r) {
            if (r < nr) {
                const float4 xv =
                    *reinterpret_cast<const float4*>(&x[(size_t)(row0 + r) * IN_F + k0]);
                acc[r] = fmaf(xv.x, w0, acc[r]);
                acc[r] = fmaf(xv.y, w1, acc[r]);
                acc[r] = fmaf(xv.z, w2, acc[r]);
                acc[r] = fmaf(xv.w, w3, acc[r]);
            }
        }
    }
    for (int r = 0; r < nr; ++r) {
        float hv = acc[r];
        h[(size_t)(row0 + r) * OUT_F + lane] = hv;
        float s1 = hv * as;
        float s2 = hv * ad;
        for (int off = 32; off; off >>= 1) {
            s1 += __shfl_xor(s1, off, 64);
            s2 += __shfl_xor(s2, off, 64);
        }
        if (lane == 0) {
            a_src[row0 + r] = s1;
            a_dst[row0 + r] = s2;
        }
    }
}

// Per edge: e = leakyrelu(a_src[s] + a_dst[d]); store; atomic segment max.
__global__ void k_edge1(const int* __restrict__ ei, const float* __restrict__ a_src,
                        const float* __restrict__ a_dst, float* __restrict__ ev,
                        unsigned* __restrict__ emax) {
    int e = blockIdx.x * blockDim.x + threadIdx.x;
    if (e >= E_TOT) return;
    int s, d;
    if (e < N_EDGES) { s = ei[e]; d = ei[N_EDGES + e]; }
    else             { s = e - N_EDGES; d = s; }
    float v = a_src[s] + a_dst[d];
    v = (v > 0.f) ? v : NEG_SLOPE * v;
    ev[e] = v;
    atomicMax(&emax[d], enc_f32(v));
}

// Per edge: p = exp(e - max[d]) (in place over ev); atomic denom sum.
__global__ void k_edge2(const int* __restrict__ ei, float* __restrict__ epv,
                        const unsigned* __restrict__ emax, float* __restrict__ denom) {
    int e = blockIdx.x * blockDim.x + threadIdx.x;
    if (e >= E_TOT) return;
    int d = (e < N_EDGES) ? ei[N_EDGES + e] : (e - N_EDGES);
    float pv = expf(epv[e] - dec_f32(emax[d]));
    epv[e] = pv;
    atomicAdd(&denom[d], pv);
}

// One wave per edge, lane = channel: out[d][c] += h[s][c] * alpha.
__global__ __launch_bounds__(256) void k_agg(
    const int* __restrict__ ei, const float* __restrict__ p,
    const float* __restrict__ denom, const float* __restrict__ h,
    float* __restrict__ out) {
    int wid = (blockIdx.x * blockDim.x + threadIdx.x) >> 6;
    int lane = threadIdx.x & 63;
    if (wid >= E_TOT) return;
    int s, d;
    if (wid < N_EDGES) { s = ei[wid]; d = ei[N_EDGES + wid]; }
    else               { s = wid - N_EDGES; d = s; }
    float alpha = p[wid] / (denom[d] + 1e-16f);
    float v = h[(size_t)s * OUT_F + lane] * alpha;
    atomicAdd(&out[(size_t)d * OUT_F + lane], v);
}

__global__ void k_final(float* __restrict__ out, const float* __restrict__ bias) {
    int i = blockIdx.x * blockDim.x + threadIdx.x;
    if (i >= N_NODES * OUT_F) return;
    float v = out[i] + bias[i & (OUT_F - 1)];
    out[i] = (v > 0.f) ? v : 0.f;
}

extern "C" void kernel_launch(void* const* d_in, const int* in_sizes, int n_in,
                              void* d_out, int out_size, void* d_ws, size_t ws_size,
                              hipStream_t stream) {
    const float* x       = (const float*)d_in[0];
    const int*   ei      = (const int*)d_in[1];
    const float* W       = (const float*)d_in[2];
    const float* att_src = (const float*)d_in[3];
    const float* att_dst = (const float*)d_in[4];
    const float* bias    = (const float*)d_in[5];
    float* out = (float*)d_out;

    char* wsp = (char*)d_ws;
    float*    h     = (float*)wsp;    wsp += (size_t)N_NODES * OUT_F * sizeof(float);
    float*    a_src = (float*)wsp;    wsp += (size_t)N_NODES * sizeof(float);
    float*    a_dst = (float*)wsp;    wsp += (size_t)N_NODES * sizeof(float);
    unsigned* emax  = (unsigned*)wsp; wsp += (size_t)N_NODES * sizeof(unsigned);
    float*    denom = (float*)wsp;    wsp += (size_t)N_NODES * sizeof(float);
    float*    epv   = (float*)wsp;    wsp += (size_t)E_TOT * sizeof(float);

    hipLaunchKernelGGL(k_init, dim3((N_NODES * OUT_F + 255) / 256), dim3(256), 0, stream,
                       out, denom, emax);
    hipLaunchKernelGGL(k_gemm, dim3((N_NODES + 4 * GEMM_ROWS - 1) / (4 * GEMM_ROWS)),
                       dim3(256), 0, stream, x, W, att_src, att_dst, h, a_src, a_dst);
    hipLaunchKernelGGL(k_edge1, dim3((E_TOT + 255) / 256), dim3(256), 0, stream,
                       ei, a_src, a_dst, epv, emax);
    hipLaunchKernelGGL(k_edge2, dim3((E_TOT + 255) / 256), dim3(256), 0, stream,
                       ei, epv, emax, denom);
    hipLaunchKernelGGL(k_agg, dim3((E_TOT + 3) / 4), dim3(256), 0, stream,
                       ei, epv, denom, h, out);
    hipLaunchKernelGGL(k_final, dim3((N_NODES * OUT_F + 255) / 256), dim3(256), 0, stream,
                       out, bias);
}

// Round 2
// 223.294 us; speedup vs baseline: 1.5564x; 1.5564x over previous
//
#include <hip/hip_runtime.h>
#include <math.h>

#define N_NODES 50000
#define N_EDGES 800000
#define IN_F 128
#define OUT_F 64
#define E_TOT (N_EDGES + N_NODES)
#define NEG_SLOPE 0.2f
#define GEMM_ROWS 8
#define SCAN_BLOCKS ((N_NODES + 255) / 256)  // 196

// Monotonic float<->uint encoding so float-max can use atomicMax(unsigned).
__device__ __forceinline__ unsigned enc_f32(float f) {
    unsigned u = __float_as_uint(f);
    return (u & 0x80000000u) ? ~u : (u | 0x80000000u);
}
__device__ __forceinline__ float dec_f32(unsigned u) {
    unsigned b = (u & 0x80000000u) ? (u & 0x7FFFFFFFu) : ~u;
    return __uint_as_float(b);
}
#define ENC_NEG_INF 0x007FFFFFu  // enc_f32(-inf)

__global__ void k_init(int* __restrict__ cnt, int* __restrict__ cur,
                       unsigned* __restrict__ emax) {
    int i = blockIdx.x * blockDim.x + threadIdx.x;
    if (i < N_NODES) { cnt[i] = 0; cur[i] = 0; emax[i] = ENC_NEG_INF; }
}

// h = x @ W  (one wave per GEMM_ROWS rows, lane = output channel)
// plus fused a_src = h@att_src, a_dst = h@att_dst via wave shuffle reduce.
__global__ __launch_bounds__(256) void k_gemm(
    const float* __restrict__ x, const float* __restrict__ W,
    const float* __restrict__ att_src, const float* __restrict__ att_dst,
    float* __restrict__ h, float* __restrict__ a_src, float* __restrict__ a_dst) {
    __shared__ float Wl[IN_F * OUT_F];  // 32 KB
    int tid = threadIdx.x;
    for (int i = tid; i < IN_F * OUT_F; i += 256) Wl[i] = W[i];
    __syncthreads();

    int wave = tid >> 6;
    int lane = tid & 63;
    float as = att_src[lane];
    float ad = att_dst[lane];

    int row0 = (blockIdx.x * 4 + wave) * GEMM_ROWS;
    if (row0 >= N_NODES) return;
    int nr = min(GEMM_ROWS, N_NODES - row0);

    float acc[GEMM_ROWS];
#pragma unroll
    for (int r = 0; r < GEMM_ROWS; ++r) acc[r] = 0.f;

    for (int k0 = 0; k0 < IN_F; k0 += 4) {
        float w0 = Wl[(k0 + 0) * OUT_F + lane];
        float w1 = Wl[(k0 + 1) * OUT_F + lane];
        float w2 = Wl[(k0 + 2) * OUT_F + lane];
        float w3 = Wl[(k0 + 3) * OUT_F + lane];
#pragma unroll
        for (int r = 0; r < GEMM_ROWS; ++r) {
            if (r < nr) {
                const float4 xv =
                    *reinterpret_cast<const float4*>(&x[(size_t)(row0 + r) * IN_F + k0]);
                acc[r] = fmaf(xv.x, w0, acc[r]);
                acc[r] = fmaf(xv.y, w1, acc[r]);
                acc[r] = fmaf(xv.z, w2, acc[r]);
                acc[r] = fmaf(xv.w, w3, acc[r]);
            }
        }
    }
    for (int r = 0; r < nr; ++r) {
        float hv = acc[r];
        h[(size_t)(row0 + r) * OUT_F + lane] = hv;
        float s1 = hv * as;
        float s2 = hv * ad;
        for (int off = 32; off; off >>= 1) {
            s1 += __shfl_xor(s1, off, 64);
            s2 += __shfl_xor(s2, off, 64);
        }
        if (lane == 0) {
            a_src[row0 + r] = s1;
            a_dst[row0 + r] = s2;
        }
    }
}

// Count incoming edges per destination.
__global__ void k_count(const int* __restrict__ ei, int* __restrict__ cnt) {
    int e = blockIdx.x * blockDim.x + threadIdx.x;
    if (e >= E_TOT) return;
    int d = (e < N_EDGES) ? ei[N_EDGES + e] : (e - N_EDGES);
    atomicAdd(&cnt[d], 1);
}

// Block-level exclusive scan of cnt -> row (local), block sums -> bsum.
__global__ __launch_bounds__(256) void k_scan_block(const int* __restrict__ cnt,
                                                    int* __restrict__ row,
                                                    int* __restrict__ bsum) {
    __shared__ int sd[256];
    int tid = threadIdx.x;
    int i = blockIdx.x * 256 + tid;
    int v = (i < N_NODES) ? cnt[i] : 0;
    sd[tid] = v;
    __syncthreads();
    for (int off = 1; off < 256; off <<= 1) {
        int t = (tid >= off) ? sd[tid - off] : 0;
        __syncthreads();
        sd[tid] += t;
        __syncthreads();
    }
    int incl = sd[tid];
    if (i < N_NODES) row[i] = incl - v;
    if (tid == 255) bsum[blockIdx.x] = incl;
}

// Scan the block sums (single block), write row[N] = E_TOT.
__global__ __launch_bounds__(256) void k_scan_top(int* __restrict__ bsum,
                                                  int* __restrict__ row) {
    __shared__ int sd[256];
    int tid = threadIdx.x;
    int v = (tid < SCAN_BLOCKS) ? bsum[tid] : 0;
    sd[tid] = v;
    __syncthreads();
    for (int off = 1; off < 256; off <<= 1) {
        int t = (tid >= off) ? sd[tid - off] : 0;
        __syncthreads();
        sd[tid] += t;
        __syncthreads();
    }
    if (tid < SCAN_BLOCKS) bsum[tid] = sd[tid] - v;  // exclusive
    if (tid == 0) row[N_NODES] = E_TOT;
}

__global__ void k_scan_add(int* __restrict__ row, const int* __restrict__ bsum) {
    int i = blockIdx.x * blockDim.x + threadIdx.x;
    if (i < N_NODES) row[i] += bsum[i >> 8];
}

// Fill CSR: per edge compute e = leakyrelu(a_src[s]+a_dst[d]), place at
// row[d] + cursor, and atomic-max into emax[d].
__global__ void k_fill(const int* __restrict__ ei, const float* __restrict__ a_src,
                       const float* __restrict__ a_dst, const int* __restrict__ row,
                       int* __restrict__ cur, int* __restrict__ csr_src,
                       float* __restrict__ csr_e, unsigned* __restrict__ emax) {
    int e = blockIdx.x * blockDim.x + threadIdx.x;
    if (e >= E_TOT) return;
    int s, d;
    if (e < N_EDGES) { s = ei[e]; d = ei[N_EDGES + e]; }
    else             { s = e - N_EDGES; d = s; }
    float v = a_src[s] + a_dst[d];
    v = (v > 0.f) ? v : NEG_SLOPE * v;
    int pos = row[d] + atomicAdd(&cur[d], 1);
    csr_src[pos] = s;
    csr_e[pos] = v;
    atomicMax(&emax[d], enc_f32(v));
}

// One wave per destination node: softmax over its CSR segment + gather-
// aggregate h[src]*alpha, fused bias+relu epilogue. No atomics.
__global__ __launch_bounds__(256) void k_node(
    const int* __restrict__ row, const int* __restrict__ csr_src,
    const float* __restrict__ csr_e, const unsigned* __restrict__ emax,
    const float* __restrict__ h, const float* __restrict__ bias,
    float* __restrict__ out) {
    int wid = (blockIdx.x * blockDim.x + threadIdx.x) >> 6;
    int lane = threadIdx.x & 63;
    if (wid >= N_NODES) return;
    int beg = row[wid];
    int end = row[wid + 1];
    float m = dec_f32(emax[wid]);
    float acc = 0.f;
    float l = 0.f;

    for (int base = beg; base < end; base += 64) {
        int n = min(64, end - base);
        float p = 0.f;
        int s = 0;
        if (lane < n) {
            s = csr_src[base + lane];
            p = expf(csr_e[base + lane] - m);
        }
        float ps = p;
        for (int off = 32; off; off >>= 1) ps += __shfl_xor(ps, off, 64);
        l += ps;

        int j = 0;
        for (; j + 1 < n; j += 2) {
            float p0 = __shfl(p, j, 64);
            int s0 = __shfl(s, j, 64);
            float p1 = __shfl(p, j + 1, 64);
            int s1 = __shfl(s, j + 1, 64);
            float h0 = h[(size_t)s0 * OUT_F + lane];
            float h1 = h[(size_t)s1 * OUT_F + lane];
            acc = fmaf(p0, h0, acc);
            acc = fmaf(p1, h1, acc);
        }
        if (j < n) {
            float p0 = __shfl(p, j, 64);
            int s0 = __shfl(s, j, 64);
            acc = fmaf(p0, h[(size_t)s0 * OUT_F + lane], acc);
        }
    }
    float v = acc / (l + 1e-16f) + bias[lane];
    out[(size_t)wid * OUT_F + lane] = (v > 0.f) ? v : 0.f;
}

extern "C" void kernel_launch(void* const* d_in, const int* in_sizes, int n_in,
                              void* d_out, int out_size, void* d_ws, size_t ws_size,
                              hipStream_t stream) {
    const float* x       = (const float*)d_in[0];
    const int*   ei      = (const int*)d_in[1];
    const float* W       = (const float*)d_in[2];
    const float* att_src = (const float*)d_in[3];
    const float* att_dst = (const float*)d_in[4];
    const float* bias    = (const float*)d_in[5];
    float* out = (float*)d_out;

    char* wsp = (char*)d_ws;
    float*    h       = (float*)wsp;    wsp += (size_t)N_NODES * OUT_F * sizeof(float);
    float*    a_src   = (float*)wsp;    wsp += (size_t)N_NODES * sizeof(float);
    float*    a_dst   = (float*)wsp;    wsp += (size_t)N_NODES * sizeof(float);
    unsigned* emax    = (unsigned*)wsp; wsp += (size_t)N_NODES * sizeof(unsigned);
    int*      cnt     = (int*)wsp;      wsp += (size_t)N_NODES * sizeof(int);
    int*      cur     = (int*)wsp;      wsp += (size_t)N_NODES * sizeof(int);
    int*      row     = (int*)wsp;      wsp += (size_t)(N_NODES + 1) * sizeof(int);
    int*      bsum    = (int*)wsp;      wsp += 256 * sizeof(int);
    int*      csr_src = (int*)wsp;      wsp += (size_t)E_TOT * sizeof(int);
    float*    csr_e   = (float*)wsp;    wsp += (size_t)E_TOT * sizeof(float);

    hipLaunchKernelGGL(k_init, dim3((N_NODES + 255) / 256), dim3(256), 0, stream,
                       cnt, cur, emax);
    hipLaunchKernelGGL(k_gemm, dim3((N_NODES + 4 * GEMM_ROWS - 1) / (4 * GEMM_ROWS)),
                       dim3(256), 0, stream, x, W, att_src, att_dst, h, a_src, a_dst);
    hipLaunchKernelGGL(k_count, dim3((E_TOT + 255) / 256), dim3(256), 0, stream, ei, cnt);
    hipLaunchKernelGGL(k_scan_block, dim3(SCAN_BLOCKS), dim3(256), 0, stream,
                       cnt, row, bsum);
    hipLaunchKernelGGL(k_scan_top, dim3(1), dim3(256), 0, stream, bsum, row);
    hipLaunchKernelGGL(k_scan_add, dim3(SCAN_BLOCKS), dim3(256), 0, stream, row, bsum);
    hipLaunchKernelGGL(k_fill, dim3((E_TOT + 255) / 256), dim3(256), 0, stream,
                       ei, a_src, a_dst, row, cur, csr_src, csr_e, emax);
    hipLaunchKernelGGL(k_node, dim3((N_NODES * 64 + 255) / 256), dim3(256), 0, stream,
                       row, csr_src, csr_e, emax, h, bias, out);
}

// Round 3
// 164.790 us; speedup vs baseline: 2.1089x; 1.3550x over previous
//
#include <hip/hip_runtime.h>
#include <math.h>

#define N_NODES 50000
#define N_EDGES 800000
#define IN_F 128
#define OUT_F 64
#define E_TOT (N_EDGES + N_NODES)
#define NEG_SLOPE 0.2f
#define GEMM_ROWS 8
#define SCAN_BLOCKS ((N_NODES + 255) / 256)  // 196

__global__ void k_init(int* __restrict__ cnt) {
    int i = blockIdx.x * blockDim.x + threadIdx.x;
    if (i < N_NODES) cnt[i] = 0;
}

// h = x @ W  (one wave per GEMM_ROWS rows, lane = output channel)
// plus fused a_src = h@att_src, a_dst = h@att_dst via wave shuffle reduce.
__global__ __launch_bounds__(256) void k_gemm(
    const float* __restrict__ x, const float* __restrict__ W,
    const float* __restrict__ att_src, const float* __restrict__ att_dst,
    float* __restrict__ h, float* __restrict__ a_src, float* __restrict__ a_dst) {
    __shared__ float Wl[IN_F * OUT_F];  // 32 KB
    int tid = threadIdx.x;
    for (int i = tid; i < IN_F * OUT_F; i += 256) Wl[i] = W[i];
    __syncthreads();

    int wave = tid >> 6;
    int lane = tid & 63;
    float as = att_src[lane];
    float ad = att_dst[lane];

    int row0 = (blockIdx.x * 4 + wave) * GEMM_ROWS;
    if (row0 >= N_NODES) return;
    int nr = min(GEMM_ROWS, N_NODES - row0);

    float acc[GEMM_ROWS];
#pragma unroll
    for (int r = 0; r < GEMM_ROWS; ++r) acc[r] = 0.f;

    for (int k0 = 0; k0 < IN_F; k0 += 4) {
        float w0 = Wl[(k0 + 0) * OUT_F + lane];
        float w1 = Wl[(k0 + 1) * OUT_F + lane];
        float w2 = Wl[(k0 + 2) * OUT_F + lane];
        float w3 = Wl[(k0 + 3) * OUT_F + lane];
#pragma unroll
        for (int r = 0; r < GEMM_ROWS; ++r) {
            if (r < nr) {
                const float4 xv =
                    *reinterpret_cast<const float4*>(&x[(size_t)(row0 + r) * IN_F + k0]);
                acc[r] = fmaf(xv.x, w0, acc[r]);
                acc[r] = fmaf(xv.y, w1, acc[r]);
                acc[r] = fmaf(xv.z, w2, acc[r]);
                acc[r] = fmaf(xv.w, w3, acc[r]);
            }
        }
    }
    for (int r = 0; r < nr; ++r) {
        float hv = acc[r];
        h[(size_t)(row0 + r) * OUT_F + lane] = hv;
        float s1 = hv * as;
        float s2 = hv * ad;
        for (int off = 32; off; off >>= 1) {
            s1 += __shfl_xor(s1, off, 64);
            s2 += __shfl_xor(s2, off, 64);
        }
        if (lane == 0) {
            a_src[row0 + r] = s1;
            a_dst[row0 + r] = s2;
        }
    }
}

// Count incoming edges per destination; remember each edge's slot within
// its destination segment (stable position for the later atomic-free fill).
__global__ void k_count(const int* __restrict__ ei, int* __restrict__ cnt,
                        int* __restrict__ kpos) {
    int e = blockIdx.x * blockDim.x + threadIdx.x;
    if (e >= E_TOT) return;
    int d = (e < N_EDGES) ? ei[N_EDGES + e] : (e - N_EDGES);
    kpos[e] = atomicAdd(&cnt[d], 1);
}

// Block-level exclusive scan of cnt -> row (local), block sums -> bsum.
__global__ __launch_bounds__(256) void k_scan_block(const int* __restrict__ cnt,
                                                    int* __restrict__ row,
                                                    int* __restrict__ bsum) {
    __shared__ int sd[256];
    int tid = threadIdx.x;
    int i = blockIdx.x * 256 + tid;
    int v = (i < N_NODES) ? cnt[i] : 0;
    sd[tid] = v;
    __syncthreads();
    for (int off = 1; off < 256; off <<= 1) {
        int t = (tid >= off) ? sd[tid - off] : 0;
        __syncthreads();
        sd[tid] += t;
        __syncthreads();
    }
    int incl = sd[tid];
    if (i < N_NODES) row[i] = incl - v;
    if (tid == 255) bsum[blockIdx.x] = incl;
}

// Scan the block sums (single block), write row[N] = E_TOT.
__global__ __launch_bounds__(256) void k_scan_top(int* __restrict__ bsum,
                                                  int* __restrict__ row) {
    __shared__ int sd[256];
    int tid = threadIdx.x;
    int v = (tid < SCAN_BLOCKS) ? bsum[tid] : 0;
    sd[tid] = v;
    __syncthreads();
    for (int off = 1; off < 256; off <<= 1) {
        int t = (tid >= off) ? sd[tid - off] : 0;
        __syncthreads();
        sd[tid] += t;
        __syncthreads();
    }
    if (tid < SCAN_BLOCKS) bsum[tid] = sd[tid] - v;  // exclusive
    if (tid == 0) row[N_NODES] = E_TOT;
}

__global__ void k_scan_add(int* __restrict__ row, const int* __restrict__ bsum) {
    int i = blockIdx.x * blockDim.x + threadIdx.x;
    if (i < N_NODES) row[i] += bsum[i >> 8];
}

// Fill CSR (no atomics): e = leakyrelu(a_src[s]+a_dst[d]) packed with src
// into one int2 at the precomputed slot row[d] + kpos[e].
__global__ void k_fill(const int* __restrict__ ei, const float* __restrict__ a_src,
                       const float* __restrict__ a_dst, const int* __restrict__ row,
                       const int* __restrict__ kpos, int2* __restrict__ csr) {
    int e = blockIdx.x * blockDim.x + threadIdx.x;
    if (e >= E_TOT) return;
    int s, d;
    if (e < N_EDGES) { s = ei[e]; d = ei[N_EDGES + e]; }
    else             { s = e - N_EDGES; d = s; }
    float v = a_src[s] + a_dst[d];
    v = (v > 0.f) ? v : NEG_SLOPE * v;
    csr[row[d] + kpos[e]] = make_int2(s, __float_as_int(v));
}

// One wave per destination node: exact segment max (pass 1), then softmax +
// gather-aggregate with 16-lane x float4 rows, 4 rows in flight. No atomics.
__global__ __launch_bounds__(256) void k_node(
    const int* __restrict__ row, const int2* __restrict__ csr,
    const float* __restrict__ h, const float* __restrict__ bias,
    float* __restrict__ out) {
    int wid = (blockIdx.x * blockDim.x + threadIdx.x) >> 6;
    int lane = threadIdx.x & 63;
    if (wid >= N_NODES) return;
    int beg = row[wid];
    int end = row[wid + 1];

    // pass 1: exact segment max (segment is L2-resident; re-read is cheap)
    float m = -INFINITY;
    for (int i = beg + lane; i < end; i += 64)
        m = fmaxf(m, __int_as_float(csr[i].y));
    for (int off = 32; off; off >>= 1) m = fmaxf(m, __shfl_xor(m, off, 64));

    // pass 2: softmax numerators + weighted feature gather
    float4 acc = {0.f, 0.f, 0.f, 0.f};
    float l = 0.f;
    int grp = lane >> 4;
    int c4 = lane & 15;
    for (int base = beg; base < end; base += 64) {
        int n = min(64, end - base);
        float p = 0.f;
        int s = 0;
        if (lane < n) {
            int2 se = csr[base + lane];
            s = se.x;
            p = expf(__int_as_float(se.y) - m);
        }
        float ps = p;
        for (int off = 32; off; off >>= 1) ps += __shfl_xor(ps, off, 64);
        l += ps;

        int jn = (n + 3) >> 2;
        for (int j = 0; j < jn; ++j) {
            int sl = 4 * j + grp;       // this group's edge within the chunk
            float pj = __shfl(p, sl, 64);  // 0 for out-of-range lanes
            int sj = __shfl(s, sl, 64);    // 0 for out-of-range lanes (safe)
            const float4 hv =
                *reinterpret_cast<const float4*>(&h[(size_t)sj * OUT_F + c4 * 4]);
            acc.x = fmaf(pj, hv.x, acc.x);
            acc.y = fmaf(pj, hv.y, acc.y);
            acc.z = fmaf(pj, hv.z, acc.z);
            acc.w = fmaf(pj, hv.w, acc.w);
        }
    }
    // combine the 4 row-groups (lanes l, l^16, l^32, l^48 share channels)
    acc.x += __shfl_xor(acc.x, 16, 64); acc.x += __shfl_xor(acc.x, 32, 64);
    acc.y += __shfl_xor(acc.y, 16, 64); acc.y += __shfl_xor(acc.y, 32, 64);
    acc.z += __shfl_xor(acc.z, 16, 64); acc.z += __shfl_xor(acc.z, 32, 64);
    acc.w += __shfl_xor(acc.w, 16, 64); acc.w += __shfl_xor(acc.w, 32, 64);

    if (lane < 16) {
        float inv = 1.f / (l + 1e-16f);
        const float4 b = *reinterpret_cast<const float4*>(&bias[c4 * 4]);
        float4 v;
        v.x = fmaxf(acc.x * inv + b.x, 0.f);
        v.y = fmaxf(acc.y * inv + b.y, 0.f);
        v.z = fmaxf(acc.z * inv + b.z, 0.f);
        v.w = fmaxf(acc.w * inv + b.w, 0.f);
        *reinterpret_cast<float4*>(&out[(size_t)wid * OUT_F + c4 * 4]) = v;
    }
}

extern "C" void kernel_launch(void* const* d_in, const int* in_sizes, int n_in,
                              void* d_out, int out_size, void* d_ws, size_t ws_size,
                              hipStream_t stream) {
    const float* x       = (const float*)d_in[0];
    const int*   ei      = (const int*)d_in[1];
    const float* W       = (const float*)d_in[2];
    const float* att_src = (const float*)d_in[3];
    const float* att_dst = (const float*)d_in[4];
    const float* bias    = (const float*)d_in[5];
    float* out = (float*)d_out;

    char* wsp = (char*)d_ws;
    float* h     = (float*)wsp; wsp += (size_t)N_NODES * OUT_F * sizeof(float);
    float* a_src = (float*)wsp; wsp += (size_t)N_NODES * sizeof(float);
    float* a_dst = (float*)wsp; wsp += (size_t)N_NODES * sizeof(float);
    int*   cnt   = (int*)wsp;   wsp += (size_t)N_NODES * sizeof(int);
    int*   row   = (int*)wsp;   wsp += (size_t)(N_NODES + 1) * sizeof(int);
    int*   bsum  = (int*)wsp;   wsp += 256 * sizeof(int);
    int*   kpos  = (int*)wsp;   wsp += (size_t)E_TOT * sizeof(int);
    wsp = (char*)(((size_t)wsp + 15) & ~(size_t)15);
    int2*  csr   = (int2*)wsp;  wsp += (size_t)E_TOT * sizeof(int2);

    hipLaunchKernelGGL(k_init, dim3((N_NODES + 255) / 256), dim3(256), 0, stream, cnt);
    hipLaunchKernelGGL(k_gemm, dim3((N_NODES + 4 * GEMM_ROWS - 1) / (4 * GEMM_ROWS)),
                       dim3(256), 0, stream, x, W, att_src, att_dst, h, a_src, a_dst);
    hipLaunchKernelGGL(k_count, dim3((E_TOT + 255) / 256), dim3(256), 0, stream,
                       ei, cnt, kpos);
    hipLaunchKernelGGL(k_scan_block, dim3(SCAN_BLOCKS), dim3(256), 0, stream,
                       cnt, row, bsum);
    hipLaunchKernelGGL(k_scan_top, dim3(1), dim3(256), 0, stream, bsum, row);
    hipLaunchKernelGGL(k_scan_add, dim3(SCAN_BLOCKS), dim3(256), 0, stream, row, bsum);
    hipLaunchKernelGGL(k_fill, dim3((E_TOT + 255) / 256), dim3(256), 0, stream,
                       ei, a_src, a_dst, row, kpos, csr);
    hipLaunchKernelGGL(k_node, dim3(((size_t)N_NODES * 64 + 255) / 256), dim3(256),
                       0, stream, row, csr, h, bias, out);
}

// Round 4
// 127.992 us; speedup vs baseline: 2.7152x; 1.2875x over previous
//
#include <hip/hip_runtime.h>
#include <math.h>

#define N_NODES 50000
#define N_EDGES 800000
#define IN_F 128
#define OUT_F 64
#define E_TOT (N_EDGES + N_NODES)
#define NEG_SLOPE 0.2f
#define SCAN_BLOCKS ((N_NODES + 255) / 256)  // 196

#define BM 64
#define BK 16
#define NSTAGE (IN_F / BK)  // 8

__global__ void k_init(int* __restrict__ cnt) {
    int i = blockIdx.x * blockDim.x + threadIdx.x;
    if (i < N_NODES) cnt[i] = 0;
}

// Tiled h = x @ W with fused a_src/a_dst. 64x64 block tile, 256 threads,
// 4x4 register tile per thread, BK=16 double-buffered LDS staging.
// All inner-loop operands come from LDS (no scalar-mem mixing).
__global__ __launch_bounds__(256) void k_gemm(
    const float* __restrict__ x, const float* __restrict__ W,
    const float* __restrict__ att_src, const float* __restrict__ att_dst,
    float* __restrict__ h, float* __restrict__ a_src, float* __restrict__ a_dst) {
    __shared__ float xs[2][BM][BK + 1];   // 2*64*17*4 = 8.7 KB
    __shared__ float ws[2][BK][OUT_F];    // 2*16*64*4 = 8 KB

    int tid = threadIdx.x;
    int tx = tid & 15;        // output col group (4 cols)
    int ty = tid >> 4;        // output row group (4 rows)
    int row0 = blockIdx.x * BM;

    // staging coords: x: 64 rows x 4 float4s; W: 16 k x 16 float4s
    int xr = tid >> 2, xk = (tid & 3) * 4;
    int wk = tid >> 4, wc = (tid & 15) * 4;
    int xrow = min(row0 + xr, N_NODES - 1);  // clamp OOB rows (values unused)

    // stage 0
    *reinterpret_cast<float4*>(&xs[0][xr][xk]) =
        *reinterpret_cast<const float4*>(&x[(size_t)xrow * IN_F + xk]);
    *reinterpret_cast<float4*>(&ws[0][wk][wc]) =
        *reinterpret_cast<const float4*>(&W[wk * OUT_F + wc]);
    __syncthreads();

    float acc[4][4];
#pragma unroll
    for (int i = 0; i < 4; ++i)
#pragma unroll
        for (int j = 0; j < 4; ++j) acc[i][j] = 0.f;

    int buf = 0;
    for (int s = 0; s < NSTAGE; ++s) {
        float4 xn, wn;
        if (s + 1 < NSTAGE) {  // issue next-stage loads before compute
            int k0 = (s + 1) * BK;
            xn = *reinterpret_cast<const float4*>(&x[(size_t)xrow * IN_F + k0 + xk]);
            wn = *reinterpret_cast<const float4*>(&W[(k0 + wk) * OUT_F + wc]);
        }
#pragma unroll
        for (int kk = 0; kk < BK; ++kk) {
            float4 wv = *reinterpret_cast<const float4*>(&ws[buf][kk][tx * 4]);
            float x0 = xs[buf][ty * 4 + 0][kk];
            float x1 = xs[buf][ty * 4 + 1][kk];
            float x2 = xs[buf][ty * 4 + 2][kk];
            float x3 = xs[buf][ty * 4 + 3][kk];
            acc[0][0] = fmaf(x0, wv.x, acc[0][0]);
            acc[0][1] = fmaf(x0, wv.y, acc[0][1]);
            acc[0][2] = fmaf(x0, wv.z, acc[0][2]);
            acc[0][3] = fmaf(x0, wv.w, acc[0][3]);
            acc[1][0] = fmaf(x1, wv.x, acc[1][0]);
            acc[1][1] = fmaf(x1, wv.y, acc[1][1]);
            acc[1][2] = fmaf(x1, wv.z, acc[1][2]);
            acc[1][3] = fmaf(x1, wv.w, acc[1][3]);
            acc[2][0] = fmaf(x2, wv.x, acc[2][0]);
            acc[2][1] = fmaf(x2, wv.y, acc[2][1]);
            acc[2][2] = fmaf(x2, wv.z, acc[2][2]);
            acc[2][3] = fmaf(x2, wv.w, acc[2][3]);
            acc[3][0] = fmaf(x3, wv.x, acc[3][0]);
            acc[3][1] = fmaf(x3, wv.y, acc[3][1]);
            acc[3][2] = fmaf(x3, wv.z, acc[3][2]);
            acc[3][3] = fmaf(x3, wv.w, acc[3][3]);
        }
        if (s + 1 < NSTAGE) {
            *reinterpret_cast<float4*>(&xs[buf ^ 1][xr][xk]) = xn;
            *reinterpret_cast<float4*>(&ws[buf ^ 1][wk][wc]) = wn;
            __syncthreads();
            buf ^= 1;
        }
    }

    // epilogue: write h rows + fused attention dots
    const float4 asv = *reinterpret_cast<const float4*>(&att_src[tx * 4]);
    const float4 adv = *reinterpret_cast<const float4*>(&att_dst[tx * 4]);
#pragma unroll
    for (int j = 0; j < 4; ++j) {
        int r = row0 + ty * 4 + j;
        if (r < N_NODES) {
            float4 v = {acc[j][0], acc[j][1], acc[j][2], acc[j][3]};
            *reinterpret_cast<float4*>(&h[(size_t)r * OUT_F + tx * 4]) = v;
            float s1 = v.x * asv.x + v.y * asv.y + v.z * asv.z + v.w * asv.w;
            float s2 = v.x * adv.x + v.y * adv.y + v.z * adv.z + v.w * adv.w;
            for (int off = 8; off; off >>= 1) {
                s1 += __shfl_xor(s1, off, 64);
                s2 += __shfl_xor(s2, off, 64);
            }
            if (tx == 0) {
                a_src[r] = s1;
                a_dst[r] = s2;
            }
        }
    }
}

// Count incoming edges per destination; remember each edge's slot within
// its destination segment (stable position for the later atomic-free fill).
__global__ void k_count(const int* __restrict__ ei, int* __restrict__ cnt,
                        int* __restrict__ kpos) {
    int e = blockIdx.x * blockDim.x + threadIdx.x;
    if (e >= E_TOT) return;
    int d = (e < N_EDGES) ? ei[N_EDGES + e] : (e - N_EDGES);
    kpos[e] = atomicAdd(&cnt[d], 1);
}

// Block-level exclusive scan of cnt -> row (local), block sums -> bsum.
__global__ __launch_bounds__(256) void k_scan_block(const int* __restrict__ cnt,
                                                    int* __restrict__ row,
                                                    int* __restrict__ bsum) {
    __shared__ int sd[256];
    int tid = threadIdx.x;
    int i = blockIdx.x * 256 + tid;
    int v = (i < N_NODES) ? cnt[i] : 0;
    sd[tid] = v;
    __syncthreads();
    for (int off = 1; off < 256; off <<= 1) {
        int t = (tid >= off) ? sd[tid - off] : 0;
        __syncthreads();
        sd[tid] += t;
        __syncthreads();
    }
    int incl = sd[tid];
    if (i < N_NODES) row[i] = incl - v;
    if (tid == 255) bsum[blockIdx.x] = incl;
}

// Scan the block sums (single block), write row[N] = E_TOT.
__global__ __launch_bounds__(256) void k_scan_top(int* __restrict__ bsum,
                                                  int* __restrict__ row) {
    __shared__ int sd[256];
    int tid = threadIdx.x;
    int v = (tid < SCAN_BLOCKS) ? bsum[tid] : 0;
    sd[tid] = v;
    __syncthreads();
    for (int off = 1; off < 256; off <<= 1) {
        int t = (tid >= off) ? sd[tid - off] : 0;
        __syncthreads();
        sd[tid] += t;
        __syncthreads();
    }
    if (tid < SCAN_BLOCKS) bsum[tid] = sd[tid] - v;  // exclusive
    if (tid == 0) row[N_NODES] = E_TOT;
}

__global__ void k_scan_add(int* __restrict__ row, const int* __restrict__ bsum) {
    int i = blockIdx.x * blockDim.x + threadIdx.x;
    if (i < N_NODES) row[i] += bsum[i >> 8];
}

// Fill CSR (no atomics): e = leakyrelu(a_src[s]+a_dst[d]) packed with src
// into one int2 at the precomputed slot row[d] + kpos[e].
__global__ void k_fill(const int* __restrict__ ei, const float* __restrict__ a_src,
                       const float* __restrict__ a_dst, const int* __restrict__ row,
                       const int* __restrict__ kpos, int2* __restrict__ csr) {
    int e = blockIdx.x * blockDim.x + threadIdx.x;
    if (e >= E_TOT) return;
    int s, d;
    if (e < N_EDGES) { s = ei[e]; d = ei[N_EDGES + e]; }
    else             { s = e - N_EDGES; d = s; }
    float v = a_src[s] + a_dst[d];
    v = (v > 0.f) ? v : NEG_SLOPE * v;
    csr[row[d] + kpos[e]] = make_int2(s, __float_as_int(v));
}

// One wave per destination node: exact segment max (pass 1), then softmax +
// gather-aggregate with 16-lane x float4 rows, 4 rows in flight. No atomics.
__global__ __launch_bounds__(256) void k_node(
    const int* __restrict__ row, const int2* __restrict__ csr,
    const float* __restrict__ h, const float* __restrict__ bias,
    float* __restrict__ out) {
    int wid = (blockIdx.x * blockDim.x + threadIdx.x) >> 6;
    int lane = threadIdx.x & 63;
    if (wid >= N_NODES) return;
    int beg = row[wid];
    int end = row[wid + 1];

    // pass 1: exact segment max (segment is L2-resident; re-read is cheap)
    float m = -INFINITY;
    for (int i = beg + lane; i < end; i += 64)
        m = fmaxf(m, __int_as_float(csr[i].y));
    for (int off = 32; off; off >>= 1) m = fmaxf(m, __shfl_xor(m, off, 64));

    // pass 2: softmax numerators + weighted feature gather
    float4 acc = {0.f, 0.f, 0.f, 0.f};
    float l = 0.f;
    int grp = lane >> 4;
    int c4 = lane & 15;
    for (int base = beg; base < end; base += 64) {
        int n = min(64, end - base);
        float p = 0.f;
        int s = 0;
        if (lane < n) {
            int2 se = csr[base + lane];
            s = se.x;
            p = expf(__int_as_float(se.y) - m);
        }
        float ps = p;
        for (int off = 32; off; off >>= 1) ps += __shfl_xor(ps, off, 64);
        l += ps;

        int jn = (n + 3) >> 2;
        for (int j = 0; j < jn; ++j) {
            int sl = 4 * j + grp;          // this group's edge within the chunk
            float pj = __shfl(p, sl, 64);  // 0 for out-of-range lanes
            int sj = __shfl(s, sl, 64);    // 0 for out-of-range lanes (safe)
            const float4 hv =
                *reinterpret_cast<const float4*>(&h[(size_t)sj * OUT_F + c4 * 4]);
            acc.x = fmaf(pj, hv.x, acc.x);
            acc.y = fmaf(pj, hv.y, acc.y);
            acc.z = fmaf(pj, hv.z, acc.z);
            acc.w = fmaf(pj, hv.w, acc.w);
        }
    }
    // combine the 4 row-groups (lanes l, l^16, l^32, l^48 share channels)
    acc.x += __shfl_xor(acc.x, 16, 64); acc.x += __shfl_xor(acc.x, 32, 64);
    acc.y += __shfl_xor(acc.y, 16, 64); acc.y += __shfl_xor(acc.y, 32, 64);
    acc.z += __shfl_xor(acc.z, 16, 64); acc.z += __shfl_xor(acc.z, 32, 64);
    acc.w += __shfl_xor(acc.w, 16, 64); acc.w += __shfl_xor(acc.w, 32, 64);

    if (lane < 16) {
        float inv = 1.f / (l + 1e-16f);
        const float4 b = *reinterpret_cast<const float4*>(&bias[c4 * 4]);
        float4 v;
        v.x = fmaxf(acc.x * inv + b.x, 0.f);
        v.y = fmaxf(acc.y * inv + b.y, 0.f);
        v.z = fmaxf(acc.z * inv + b.z, 0.f);
        v.w = fmaxf(acc.w * inv + b.w, 0.f);
        *reinterpret_cast<float4*>(&out[(size_t)wid * OUT_F + c4 * 4]) = v;
    }
}

extern "C" void kernel_launch(void* const* d_in, const int* in_sizes, int n_in,
                              void* d_out, int out_size, void* d_ws, size_t ws_size,
                              hipStream_t stream) {
    const float* x       = (const float*)d_in[0];
    const int*   ei      = (const int*)d_in[1];
    const float* W       = (const float*)d_in[2];
    const float* att_src = (const float*)d_in[3];
    const float* att_dst = (const float*)d_in[4];
    const float* bias    = (const float*)d_in[5];
    float* out = (float*)d_out;

    char* wsp = (char*)d_ws;
    float* h     = (float*)wsp; wsp += (size_t)N_NODES * OUT_F * sizeof(float);
    float* a_src = (float*)wsp; wsp += (size_t)N_NODES * sizeof(float);
    float* a_dst = (float*)wsp; wsp += (size_t)N_NODES * sizeof(float);
    int*   cnt   = (int*)wsp;   wsp += (size_t)N_NODES * sizeof(int);
    int*   row   = (int*)wsp;   wsp += (size_t)(N_NODES + 1) * sizeof(int);
    int*   bsum  = (int*)wsp;   wsp += 256 * sizeof(int);
    int*   kpos  = (int*)wsp;   wsp += (size_t)E_TOT * sizeof(int);
    wsp = (char*)(((size_t)wsp + 15) & ~(size_t)15);
    int2*  csr   = (int2*)wsp;  wsp += (size_t)E_TOT * sizeof(int2);

    hipLaunchKernelGGL(k_init, dim3((N_NODES + 255) / 256), dim3(256), 0, stream, cnt);
    hipLaunchKernelGGL(k_gemm, dim3((N_NODES + BM - 1) / BM), dim3(256), 0, stream,
                       x, W, att_src, att_dst, h, a_src, a_dst);
    hipLaunchKernelGGL(k_count, dim3((E_TOT + 255) / 256), dim3(256), 0, stream,
                       ei, cnt, kpos);
    hipLaunchKernelGGL(k_scan_block, dim3(SCAN_BLOCKS), dim3(256), 0, stream,
                       cnt, row, bsum);
    hipLaunchKernelGGL(k_scan_top, dim3(1), dim3(256), 0, stream, bsum, row);
    hipLaunchKernelGGL(k_scan_add, dim3(SCAN_BLOCKS), dim3(256), 0, stream, row, bsum);
    hipLaunchKernelGGL(k_fill, dim3((E_TOT + 255) / 256), dim3(256), 0, stream,
                       ei, a_src, a_dst, row, kpos, csr);
    hipLaunchKernelGGL(k_node, dim3(((size_t)N_NODES * 64 + 255) / 256), dim3(256),
                       0, stream, row, csr, h, bias, out);
}

// Round 5
// 114.030 us; speedup vs baseline: 3.0477x; 1.1224x over previous
//
#include <hip/hip_runtime.h>
#include <math.h>

#define N_NODES 50000
#define N_EDGES 800000
#define IN_F 128
#define OUT_F 64
#define E_TOT (N_EDGES + N_NODES)
#define NEG_SLOPE 0.2f
#define SCAN_BLOCKS ((N_NODES + 255) / 256)  // 196

#define BM 64
#define BK 16
#define NSTAGE (IN_F / BK)  // 8

// fp32 -> bf16 with round-to-nearest-even
__device__ __forceinline__ unsigned short f2bf(float f) {
    unsigned u = __float_as_uint(f);
    return (unsigned short)((u + 0x7FFFu + ((u >> 16) & 1u)) >> 16);
}

// Tiled h = x @ W with fused a_src/a_dst epilogue; h stored in bf16.
// Also zeroes cnt[] (fused former k_init).
__global__ __launch_bounds__(256) void k_gemm(
    const float* __restrict__ x, const float* __restrict__ W,
    const float* __restrict__ att_src, const float* __restrict__ att_dst,
    unsigned short* __restrict__ h, float* __restrict__ a_src,
    float* __restrict__ a_dst, int* __restrict__ cnt) {
    __shared__ float xs[2][BM][BK + 1];
    __shared__ float ws[2][BK][OUT_F];

    int tid = threadIdx.x;
    int g = blockIdx.x * 256 + tid;
    if (g < N_NODES) cnt[g] = 0;  // fused init (cnt only used by later kernels)

    int tx = tid & 15;   // output col group (4 cols)
    int ty = tid >> 4;   // output row group (4 rows)
    int row0 = blockIdx.x * BM;

    int xr = tid >> 2, xk = (tid & 3) * 4;
    int wk = tid >> 4, wc = (tid & 15) * 4;
    int xrow = min(row0 + xr, N_NODES - 1);  // clamp OOB rows (values unused)

    *reinterpret_cast<float4*>(&xs[0][xr][xk]) =
        *reinterpret_cast<const float4*>(&x[(size_t)xrow * IN_F + xk]);
    *reinterpret_cast<float4*>(&ws[0][wk][wc]) =
        *reinterpret_cast<const float4*>(&W[wk * OUT_F + wc]);
    __syncthreads();

    float acc[4][4];
#pragma unroll
    for (int i = 0; i < 4; ++i)
#pragma unroll
        for (int j = 0; j < 4; ++j) acc[i][j] = 0.f;

    int buf = 0;
    for (int s = 0; s < NSTAGE; ++s) {
        float4 xn, wn;
        if (s + 1 < NSTAGE) {
            int k0 = (s + 1) * BK;
            xn = *reinterpret_cast<const float4*>(&x[(size_t)xrow * IN_F + k0 + xk]);
            wn = *reinterpret_cast<const float4*>(&W[(k0 + wk) * OUT_F + wc]);
        }
#pragma unroll
        for (int kk = 0; kk < BK; ++kk) {
            float4 wv = *reinterpret_cast<const float4*>(&ws[buf][kk][tx * 4]);
            float x0 = xs[buf][ty * 4 + 0][kk];
            float x1 = xs[buf][ty * 4 + 1][kk];
            float x2 = xs[buf][ty * 4 + 2][kk];
            float x3 = xs[buf][ty * 4 + 3][kk];
            acc[0][0] = fmaf(x0, wv.x, acc[0][0]);
            acc[0][1] = fmaf(x0, wv.y, acc[0][1]);
            acc[0][2] = fmaf(x0, wv.z, acc[0][2]);
            acc[0][3] = fmaf(x0, wv.w, acc[0][3]);
            acc[1][0] = fmaf(x1, wv.x, acc[1][0]);
            acc[1][1] = fmaf(x1, wv.y, acc[1][1]);
            acc[1][2] = fmaf(x1, wv.z, acc[1][2]);
            acc[1][3] = fmaf(x1, wv.w, acc[1][3]);
            acc[2][0] = fmaf(x2, wv.x, acc[2][0]);
            acc[2][1] = fmaf(x2, wv.y, acc[2][1]);
            acc[2][2] = fmaf(x2, wv.z, acc[2][2]);
            acc[2][3] = fmaf(x2, wv.w, acc[2][3]);
            acc[3][0] = fmaf(x3, wv.x, acc[3][0]);
            acc[3][1] = fmaf(x3, wv.y, acc[3][1]);
            acc[3][2] = fmaf(x3, wv.z, acc[3][2]);
            acc[3][3] = fmaf(x3, wv.w, acc[3][3]);
        }
        if (s + 1 < NSTAGE) {
            *reinterpret_cast<float4*>(&xs[buf ^ 1][xr][xk]) = xn;
            *reinterpret_cast<float4*>(&ws[buf ^ 1][wk][wc]) = wn;
            __syncthreads();
            buf ^= 1;
        }
    }

    const float4 asv = *reinterpret_cast<const float4*>(&att_src[tx * 4]);
    const float4 adv = *reinterpret_cast<const float4*>(&att_dst[tx * 4]);
#pragma unroll
    for (int j = 0; j < 4; ++j) {
        int r = row0 + ty * 4 + j;
        if (r < N_NODES) {
            ushort4 hv;
            hv.x = f2bf(acc[j][0]);
            hv.y = f2bf(acc[j][1]);
            hv.z = f2bf(acc[j][2]);
            hv.w = f2bf(acc[j][3]);
            *reinterpret_cast<ushort4*>(&h[(size_t)r * OUT_F + tx * 4]) = hv;
            float s1 = acc[j][0] * asv.x + acc[j][1] * asv.y +
                       acc[j][2] * asv.z + acc[j][3] * asv.w;
            float s2 = acc[j][0] * adv.x + acc[j][1] * adv.y +
                       acc[j][2] * adv.z + acc[j][3] * adv.w;
            for (int off = 8; off; off >>= 1) {
                s1 += __shfl_xor(s1, off, 64);
                s2 += __shfl_xor(s2, off, 64);
            }
            if (tx == 0) {
                a_src[r] = s1;
                a_dst[r] = s2;
            }
        }
    }
}

// Count incoming edges per destination; kpos = edge's slot in its segment.
__global__ void k_count(const int* __restrict__ ei, int* __restrict__ cnt,
                        int* __restrict__ kpos) {
    int e = blockIdx.x * blockDim.x + threadIdx.x;
    if (e >= E_TOT) return;
    int d = (e < N_EDGES) ? ei[N_EDGES + e] : (e - N_EDGES);
    kpos[e] = atomicAdd(&cnt[d], 1);
}

__global__ __launch_bounds__(256) void k_scan_block(const int* __restrict__ cnt,
                                                    int* __restrict__ row,
                                                    int* __restrict__ bsum) {
    __shared__ int sd[256];
    int tid = threadIdx.x;
    int i = blockIdx.x * 256 + tid;
    int v = (i < N_NODES) ? cnt[i] : 0;
    sd[tid] = v;
    __syncthreads();
    for (int off = 1; off < 256; off <<= 1) {
        int t = (tid >= off) ? sd[tid - off] : 0;
        __syncthreads();
        sd[tid] += t;
        __syncthreads();
    }
    int incl = sd[tid];
    if (i < N_NODES) row[i] = incl - v;
    if (tid == 255) bsum[blockIdx.x] = incl;
}

__global__ __launch_bounds__(256) void k_scan_top(int* __restrict__ bsum,
                                                  int* __restrict__ row) {
    __shared__ int sd[256];
    int tid = threadIdx.x;
    int v = (tid < SCAN_BLOCKS) ? bsum[tid] : 0;
    sd[tid] = v;
    __syncthreads();
    for (int off = 1; off < 256; off <<= 1) {
        int t = (tid >= off) ? sd[tid - off] : 0;
        __syncthreads();
        sd[tid] += t;
        __syncthreads();
    }
    if (tid < SCAN_BLOCKS) bsum[tid] = sd[tid] - v;  // exclusive
    if (tid == 0) row[N_NODES] = E_TOT;
}

__global__ void k_scan_add(int* __restrict__ row, const int* __restrict__ bsum) {
    int i = blockIdx.x * blockDim.x + threadIdx.x;
    if (i < N_NODES) row[i] += bsum[i >> 8];
}

// Pure permutation scatter: csr_src[row[d] + kpos[e]] = s. No attention math.
__global__ void k_fill(const int* __restrict__ ei, const int* __restrict__ row,
                       const int* __restrict__ kpos, int* __restrict__ csr_src) {
    int e = blockIdx.x * blockDim.x + threadIdx.x;
    if (e >= E_TOT) return;
    int s, d;
    if (e < N_EDGES) { s = ei[e]; d = ei[N_EDGES + e]; }
    else             { s = e - N_EDGES; d = s; }
    csr_src[row[d] + kpos[e]] = s;
}

// One wave per destination node: recompute logits from L2-resident a-arrays,
// exact segment softmax, bf16 h gather-aggregate (16 lanes x 8B, 4 rows in
// flight), fused bias+relu. No atomics.
__global__ __launch_bounds__(256) void k_node(
    const int* __restrict__ row, const int* __restrict__ csr_src,
    const float* __restrict__ a_src, const float* __restrict__ a_dst,
    const unsigned short* __restrict__ h, const float* __restrict__ bias,
    float* __restrict__ out) {
    int wid = (blockIdx.x * blockDim.x + threadIdx.x) >> 6;
    int lane = threadIdx.x & 63;
    if (wid >= N_NODES) return;
    int beg = row[wid];
    int end = row[wid + 1];
    int n = end - beg;
    float a_d = a_dst[wid];  // wave-uniform

    int grp = lane >> 4;
    int c4 = lane & 15;
    float4 acc = {0.f, 0.f, 0.f, 0.f};
    float l = 0.f;

    if (n <= 64) {
        // fast path: segment fits one chunk; s,v live in registers
        int s = 0;
        float v = -INFINITY;
        if (lane < n) {
            s = csr_src[beg + lane];
            float t = a_src[s] + a_d;
            v = (t > 0.f) ? t : NEG_SLOPE * t;
        }
        float m = v;
        for (int off = 32; off; off >>= 1) m = fmaxf(m, __shfl_xor(m, off, 64));
        float p = (lane < n) ? __expf(v - m) : 0.f;
        l = p;
        for (int off = 32; off; off >>= 1) l += __shfl_xor(l, off, 64);

        int jn = (n + 3) >> 2;
        for (int j = 0; j < jn; ++j) {
            int sl = 4 * j + grp;
            float pj = __shfl(p, sl, 64);
            int sj = __shfl(s, sl, 64);
            if (sl < n) {
                uint2 hv = *reinterpret_cast<const uint2*>(&h[(size_t)sj * OUT_F + c4 * 4]);
                float f0 = __uint_as_float(hv.x << 16);
                float f1 = __uint_as_float(hv.x & 0xFFFF0000u);
                float f2 = __uint_as_float(hv.y << 16);
                float f3 = __uint_as_float(hv.y & 0xFFFF0000u);
                acc.x = fmaf(pj, f0, acc.x);
                acc.y = fmaf(pj, f1, acc.y);
                acc.z = fmaf(pj, f2, acc.z);
                acc.w = fmaf(pj, f3, acc.w);
            }
        }
    } else {
        // general path: two passes over chunks (csr/a re-reads hit cache)
        float m = -INFINITY;
        for (int i = beg + lane; i < end; i += 64) {
            float t = a_src[csr_src[i]] + a_d;
            t = (t > 0.f) ? t : NEG_SLOPE * t;
            m = fmaxf(m, t);
        }
        for (int off = 32; off; off >>= 1) m = fmaxf(m, __shfl_xor(m, off, 64));

        for (int base = beg; base < end; base += 64) {
            int nn = min(64, end - base);
            int s = 0;
            float p = 0.f;
            if (lane < nn) {
                s = csr_src[base + lane];
                float t = a_src[s] + a_d;
                t = (t > 0.f) ? t : NEG_SLOPE * t;
                p = __expf(t - m);
            }
            float ps = p;
            for (int off = 32; off; off >>= 1) ps += __shfl_xor(ps, off, 64);
            l += ps;

            int jn = (nn + 3) >> 2;
            for (int j = 0; j < jn; ++j) {
                int sl = 4 * j + grp;
                float pj = __shfl(p, sl, 64);
                int sj = __shfl(s, sl, 64);
                if (sl < nn) {
                    uint2 hv =
                        *reinterpret_cast<const uint2*>(&h[(size_t)sj * OUT_F + c4 * 4]);
                    float f0 = __uint_as_float(hv.x << 16);
                    float f1 = __uint_as_float(hv.x & 0xFFFF0000u);
                    float f2 = __uint_as_float(hv.y << 16);
                    float f3 = __uint_as_float(hv.y & 0xFFFF0000u);
                    acc.x = fmaf(pj, f0, acc.x);
                    acc.y = fmaf(pj, f1, acc.y);
                    acc.z = fmaf(pj, f2, acc.z);
                    acc.w = fmaf(pj, f3, acc.w);
                }
            }
        }
    }

    acc.x += __shfl_xor(acc.x, 16, 64); acc.x += __shfl_xor(acc.x, 32, 64);
    acc.y += __shfl_xor(acc.y, 16, 64); acc.y += __shfl_xor(acc.y, 32, 64);
    acc.z += __shfl_xor(acc.z, 16, 64); acc.z += __shfl_xor(acc.z, 32, 64);
    acc.w += __shfl_xor(acc.w, 16, 64); acc.w += __shfl_xor(acc.w, 32, 64);

    if (lane < 16) {
        float inv = 1.f / (l + 1e-16f);
        const float4 b = *reinterpret_cast<const float4*>(&bias[c4 * 4]);
        float4 v;
        v.x = fmaxf(acc.x * inv + b.x, 0.f);
        v.y = fmaxf(acc.y * inv + b.y, 0.f);
        v.z = fmaxf(acc.z * inv + b.z, 0.f);
        v.w = fmaxf(acc.w * inv + b.w, 0.f);
        *reinterpret_cast<float4*>(&out[(size_t)wid * OUT_F + c4 * 4]) = v;
    }
}

extern "C" void kernel_launch(void* const* d_in, const int* in_sizes, int n_in,
                              void* d_out, int out_size, void* d_ws, size_t ws_size,
                              hipStream_t stream) {
    const float* x       = (const float*)d_in[0];
    const int*   ei      = (const int*)d_in[1];
    const float* W       = (const float*)d_in[2];
    const float* att_src = (const float*)d_in[3];
    const float* att_dst = (const float*)d_in[4];
    const float* bias    = (const float*)d_in[5];
    float* out = (float*)d_out;

    char* wsp = (char*)d_ws;
    unsigned short* h = (unsigned short*)wsp; wsp += (size_t)N_NODES * OUT_F * sizeof(unsigned short);
    float* a_src   = (float*)wsp; wsp += (size_t)N_NODES * sizeof(float);
    float* a_dst   = (float*)wsp; wsp += (size_t)N_NODES * sizeof(float);
    int*   cnt     = (int*)wsp;   wsp += (size_t)N_NODES * sizeof(int);
    int*   row     = (int*)wsp;   wsp += (size_t)(N_NODES + 1) * sizeof(int);
    int*   bsum    = (int*)wsp;   wsp += 256 * sizeof(int);
    int*   kpos    = (int*)wsp;   wsp += (size_t)E_TOT * sizeof(int);
    int*   csr_src = (int*)wsp;   wsp += (size_t)E_TOT * sizeof(int);

    hipLaunchKernelGGL(k_gemm, dim3((N_NODES + BM - 1) / BM), dim3(256), 0, stream,
                       x, W, att_src, att_dst, h, a_src, a_dst, cnt);
    hipLaunchKernelGGL(k_count, dim3((E_TOT + 255) / 256), dim3(256), 0, stream,
                       ei, cnt, kpos);
    hipLaunchKernelGGL(k_scan_block, dim3(SCAN_BLOCKS), dim3(256), 0, stream,
                       cnt, row, bsum);
    hipLaunchKernelGGL(k_scan_top, dim3(1), dim3(256), 0, stream, bsum, row);
    hipLaunchKernelGGL(k_scan_add, dim3(SCAN_BLOCKS), dim3(256), 0, stream, row, bsum);
    hipLaunchKernelGGL(k_fill, dim3((E_TOT + 255) / 256), dim3(256), 0, stream,
                       ei, row, kpos, csr_src);
    hipLaunchKernelGGL(k_node, dim3(((size_t)N_NODES * 64 + 255) / 256), dim3(256),
                       0, stream, row, csr_src, a_src, a_dst, h, bias, out);
}

// Round 6
// 107.624 us; speedup vs baseline: 3.2291x; 1.0595x over previous
//
#include <hip/hip_runtime.h>
#include <math.h>

#define N_NODES 50000
#define N_EDGES 800000
#define IN_F 128
#define OUT_F 64
#define E_TOT (N_EDGES + N_NODES)
#define NEG_SLOPE 0.2f
#define SCAN_BLOCKS ((N_NODES + 255) / 256)  // 196

#define BM 64
#define BK 16
#define NSTAGE (IN_F / BK)  // 8

// fp32 -> bf16 with round-to-nearest-even
__device__ __forceinline__ unsigned short f2bf(float f) {
    unsigned u = __float_as_uint(f);
    return (unsigned short)((u + 0x7FFFu + ((u >> 16) & 1u)) >> 16);
}

// Tiled h = x @ W with fused a_src/a_dst epilogue; h stored in bf16.
// Also zeroes cnt[] (fused init).
__global__ __launch_bounds__(256) void k_gemm(
    const float* __restrict__ x, const float* __restrict__ W,
    const float* __restrict__ att_src, const float* __restrict__ att_dst,
    unsigned short* __restrict__ h, float* __restrict__ a_src,
    float* __restrict__ a_dst, int* __restrict__ cnt) {
    __shared__ float xs[2][BM][BK + 1];
    __shared__ float ws[2][BK][OUT_F];

    int tid = threadIdx.x;
    int g = blockIdx.x * 256 + tid;
    if (g < N_NODES) cnt[g] = 0;

    int tx = tid & 15;   // output col group (4 cols)
    int ty = tid >> 4;   // output row group (4 rows)
    int row0 = blockIdx.x * BM;

    int xr = tid >> 2, xk = (tid & 3) * 4;
    int wk = tid >> 4, wc = (tid & 15) * 4;
    int xrow = min(row0 + xr, N_NODES - 1);  // clamp OOB rows (values unused)

    *reinterpret_cast<float4*>(&xs[0][xr][xk]) =
        *reinterpret_cast<const float4*>(&x[(size_t)xrow * IN_F + xk]);
    *reinterpret_cast<float4*>(&ws[0][wk][wc]) =
        *reinterpret_cast<const float4*>(&W[wk * OUT_F + wc]);
    __syncthreads();

    float acc[4][4];
#pragma unroll
    for (int i = 0; i < 4; ++i)
#pragma unroll
        for (int j = 0; j < 4; ++j) acc[i][j] = 0.f;

    int buf = 0;
    for (int s = 0; s < NSTAGE; ++s) {
        float4 xn, wn;
        if (s + 1 < NSTAGE) {
            int k0 = (s + 1) * BK;
            xn = *reinterpret_cast<const float4*>(&x[(size_t)xrow * IN_F + k0 + xk]);
            wn = *reinterpret_cast<const float4*>(&W[(k0 + wk) * OUT_F + wc]);
        }
#pragma unroll
        for (int kk = 0; kk < BK; ++kk) {
            float4 wv = *reinterpret_cast<const float4*>(&ws[buf][kk][tx * 4]);
            float x0 = xs[buf][ty * 4 + 0][kk];
            float x1 = xs[buf][ty * 4 + 1][kk];
            float x2 = xs[buf][ty * 4 + 2][kk];
            float x3 = xs[buf][ty * 4 + 3][kk];
            acc[0][0] = fmaf(x0, wv.x, acc[0][0]);
            acc[0][1] = fmaf(x0, wv.y, acc[0][1]);
            acc[0][2] = fmaf(x0, wv.z, acc[0][2]);
            acc[0][3] = fmaf(x0, wv.w, acc[0][3]);
            acc[1][0] = fmaf(x1, wv.x, acc[1][0]);
            acc[1][1] = fmaf(x1, wv.y, acc[1][1]);
            acc[1][2] = fmaf(x1, wv.z, acc[1][2]);
            acc[1][3] = fmaf(x1, wv.w, acc[1][3]);
            acc[2][0] = fmaf(x2, wv.x, acc[2][0]);
            acc[2][1] = fmaf(x2, wv.y, acc[2][1]);
            acc[2][2] = fmaf(x2, wv.z, acc[2][2]);
            acc[2][3] = fmaf(x2, wv.w, acc[2][3]);
            acc[3][0] = fmaf(x3, wv.x, acc[3][0]);
            acc[3][1] = fmaf(x3, wv.y, acc[3][1]);
            acc[3][2] = fmaf(x3, wv.z, acc[3][2]);
            acc[3][3] = fmaf(x3, wv.w, acc[3][3]);
        }
        if (s + 1 < NSTAGE) {
            *reinterpret_cast<float4*>(&xs[buf ^ 1][xr][xk]) = xn;
            *reinterpret_cast<float4*>(&ws[buf ^ 1][wk][wc]) = wn;
            __syncthreads();
            buf ^= 1;
        }
    }

    const float4 asv = *reinterpret_cast<const float4*>(&att_src[tx * 4]);
    const float4 adv = *reinterpret_cast<const float4*>(&att_dst[tx * 4]);
#pragma unroll
    for (int j = 0; j < 4; ++j) {
        int r = row0 + ty * 4 + j;
        if (r < N_NODES) {
            ushort4 hv;
            hv.x = f2bf(acc[j][0]);
            hv.y = f2bf(acc[j][1]);
            hv.z = f2bf(acc[j][2]);
            hv.w = f2bf(acc[j][3]);
            *reinterpret_cast<ushort4*>(&h[(size_t)r * OUT_F + tx * 4]) = hv;
            float s1 = acc[j][0] * asv.x + acc[j][1] * asv.y +
                       acc[j][2] * asv.z + acc[j][3] * asv.w;
            float s2 = acc[j][0] * adv.x + acc[j][1] * adv.y +
                       acc[j][2] * adv.z + acc[j][3] * adv.w;
            for (int off = 8; off; off >>= 1) {
                s1 += __shfl_xor(s1, off, 64);
                s2 += __shfl_xor(s2, off, 64);
            }
            if (tx == 0) {
                a_src[r] = s1;
                a_dst[r] = s2;
            }
        }
    }
}

// Count incoming edges per destination; pack (slot<<16 | dst) per edge
// (both fit 16 bits: N_NODES=50000 < 65536, max degree << 65536).
__global__ void k_count(const int* __restrict__ ei, int* __restrict__ cnt,
                        unsigned* __restrict__ posd) {
    int e = blockIdx.x * blockDim.x + threadIdx.x;
    if (e >= E_TOT) return;
    int d = (e < N_EDGES) ? ei[N_EDGES + e] : (e - N_EDGES);
    unsigned k = (unsigned)atomicAdd(&cnt[d], 1);
    posd[e] = (k << 16) | (unsigned)d;
}

// Block-level exclusive scan of cnt -> row (local), block sums -> bsum.
__global__ __launch_bounds__(256) void k_scan_block(const int* __restrict__ cnt,
                                                    int* __restrict__ row,
                                                    int* __restrict__ bsum) {
    __shared__ int sd[256];
    int tid = threadIdx.x;
    int i = blockIdx.x * 256 + tid;
    int v = (i < N_NODES) ? cnt[i] : 0;
    sd[tid] = v;
    __syncthreads();
    for (int off = 1; off < 256; off <<= 1) {
        int t = (tid >= off) ? sd[tid - off] : 0;
        __syncthreads();
        sd[tid] += t;
        __syncthreads();
    }
    int incl = sd[tid];
    if (i < N_NODES) row[i] = incl - v;
    if (tid == 255) bsum[blockIdx.x] = incl;
}

// Merged top-scan + add: every block re-scans the 196 block sums in LDS,
// picks its own exclusive prefix, adds to its row entries.
__global__ __launch_bounds__(256) void k_scan_top_add(int* __restrict__ row,
                                                      const int* __restrict__ bsum) {
    __shared__ int sd[256];
    __shared__ int sex;
    int tid = threadIdx.x;
    int v = (tid < SCAN_BLOCKS) ? bsum[tid] : 0;
    sd[tid] = v;
    __syncthreads();
    for (int off = 1; off < 256; off <<= 1) {
        int t = (tid >= off) ? sd[tid - off] : 0;
        __syncthreads();
        sd[tid] += t;
        __syncthreads();
    }
    if (tid == blockIdx.x) sex = sd[tid] - v;  // exclusive prefix of this block
    __syncthreads();
    int i = blockIdx.x * 256 + tid;
    if (i < N_NODES) row[i] += sex;
    if (i == 0) row[N_NODES] = E_TOT;
}

// Pure permutation scatter: csr_src[row[d] + slot] = (u16)s.
__global__ void k_fill(const int* __restrict__ ei, const int* __restrict__ row,
                       const unsigned* __restrict__ posd,
                       unsigned short* __restrict__ csr_src) {
    int e = blockIdx.x * blockDim.x + threadIdx.x;
    if (e >= E_TOT) return;
    int s = (e < N_EDGES) ? ei[e] : (e - N_EDGES);
    unsigned pd = posd[e];
    csr_src[row[pd & 0xFFFFu] + (pd >> 16)] = (unsigned short)s;
}

// Two nodes per wave (32 lanes each, two 16-lane gather groups per node):
// recompute logits from L2-resident a-arrays, exact segment softmax, bf16
// h gather-aggregate, fused bias+relu. No atomics.
__global__ __launch_bounds__(256) void k_node(
    const int* __restrict__ row, const unsigned short* __restrict__ csr_src,
    const float* __restrict__ a_src, const float* __restrict__ a_dst,
    const unsigned short* __restrict__ h, const float* __restrict__ bias,
    float* __restrict__ out) {
    int wpair = (blockIdx.x * blockDim.x + threadIdx.x) >> 6;
    int lane = threadIdx.x & 63;
    int half = lane >> 5;
    int hl = lane & 31;
    int node = wpair * 2 + half;
    if (node >= N_NODES) return;  // N_NODES even: whole wave uniform
    int beg = row[node];
    int end = row[node + 1];
    int n = end - beg;
    float a_d = a_dst[node];

    int g2 = hl >> 4;     // 16-lane group within half
    int c4 = lane & 15;   // channel quad
    int hbase = half << 5;
    float4 acc = {0.f, 0.f, 0.f, 0.f};
    float l = 0.f;

    if (n <= 32) {
        // fast path: whole segment in the half's registers
        int s = 0;
        float v = -INFINITY;
        if (hl < n) {
            s = csr_src[beg + hl];
            float t = a_src[s] + a_d;
            v = (t > 0.f) ? t : NEG_SLOPE * t;
        }
        float m = v;
        for (int off = 16; off; off >>= 1) m = fmaxf(m, __shfl_xor(m, off, 64));
        float p = (hl < n) ? __expf(v - m) : 0.f;
        l = p;
        for (int off = 16; off; off >>= 1) l += __shfl_xor(l, off, 64);

        int jn = (n + 1) >> 1;
        for (int j = 0; j < jn; ++j) {
            int sl = 2 * j + g2;
            float pj = __shfl(p, hbase + sl, 64);
            int sj = __shfl(s, hbase + sl, 64);
            if (sl < n) {
                uint2 hv = *reinterpret_cast<const uint2*>(&h[(size_t)sj * OUT_F + c4 * 4]);
                acc.x = fmaf(pj, __uint_as_float(hv.x << 16), acc.x);
                acc.y = fmaf(pj, __uint_as_float(hv.x & 0xFFFF0000u), acc.y);
                acc.z = fmaf(pj, __uint_as_float(hv.y << 16), acc.z);
                acc.w = fmaf(pj, __uint_as_float(hv.y & 0xFFFF0000u), acc.w);
            }
        }
    } else {
        // general path (rare): 32-wide chunked two-pass
        float m = -INFINITY;
        for (int i = beg + hl; i < end; i += 32) {
            float t = a_src[csr_src[i]] + a_d;
            t = (t > 0.f) ? t : NEG_SLOPE * t;
            m = fmaxf(m, t);
        }
        for (int off = 16; off; off >>= 1) m = fmaxf(m, __shfl_xor(m, off, 64));

        for (int base = beg; base < end; base += 32) {
            int nn = min(32, end - base);
            int s = 0;
            float p = 0.f;
            if (hl < nn) {
                s = csr_src[base + hl];
                float t = a_src[s] + a_d;
                t = (t > 0.f) ? t : NEG_SLOPE * t;
                p = __expf(t - m);
            }
            float ps = p;
            for (int off = 16; off; off >>= 1) ps += __shfl_xor(ps, off, 64);
            l += ps;

            int jn = (nn + 1) >> 1;
            for (int j = 0; j < jn; ++j) {
                int sl = 2 * j + g2;
                float pj = __shfl(p, hbase + sl, 64);
                int sj = __shfl(s, hbase + sl, 64);
                if (sl < nn) {
                    uint2 hv =
                        *reinterpret_cast<const uint2*>(&h[(size_t)sj * OUT_F + c4 * 4]);
                    acc.x = fmaf(pj, __uint_as_float(hv.x << 16), acc.x);
                    acc.y = fmaf(pj, __uint_as_float(hv.x & 0xFFFF0000u), acc.y);
                    acc.z = fmaf(pj, __uint_as_float(hv.y << 16), acc.z);
                    acc.w = fmaf(pj, __uint_as_float(hv.y & 0xFFFF0000u), acc.w);
                }
            }
        }
    }

    // combine the 2 gather groups within each half
    acc.x += __shfl_xor(acc.x, 16, 64);
    acc.y += __shfl_xor(acc.y, 16, 64);
    acc.z += __shfl_xor(acc.z, 16, 64);
    acc.w += __shfl_xor(acc.w, 16, 64);

    if (hl < 16) {
        float inv = 1.f / (l + 1e-16f);
        const float4 b = *reinterpret_cast<const float4*>(&bias[c4 * 4]);
        float4 v;
        v.x = fmaxf(acc.x * inv + b.x, 0.f);
        v.y = fmaxf(acc.y * inv + b.y, 0.f);
        v.z = fmaxf(acc.z * inv + b.z, 0.f);
        v.w = fmaxf(acc.w * inv + b.w, 0.f);
        *reinterpret_cast<float4*>(&out[(size_t)node * OUT_F + c4 * 4]) = v;
    }
}

extern "C" void kernel_launch(void* const* d_in, const int* in_sizes, int n_in,
                              void* d_out, int out_size, void* d_ws, size_t ws_size,
                              hipStream_t stream) {
    const float* x       = (const float*)d_in[0];
    const int*   ei      = (const int*)d_in[1];
    const float* W       = (const float*)d_in[2];
    const float* att_src = (const float*)d_in[3];
    const float* att_dst = (const float*)d_in[4];
    const float* bias    = (const float*)d_in[5];
    float* out = (float*)d_out;

    char* wsp = (char*)d_ws;
    unsigned short* h = (unsigned short*)wsp;
    wsp += (size_t)N_NODES * OUT_F * sizeof(unsigned short);
    float* a_src = (float*)wsp; wsp += (size_t)N_NODES * sizeof(float);
    float* a_dst = (float*)wsp; wsp += (size_t)N_NODES * sizeof(float);
    int*   cnt   = (int*)wsp;   wsp += (size_t)N_NODES * sizeof(int);
    int*   row   = (int*)wsp;   wsp += (size_t)(N_NODES + 1) * sizeof(int);
    int*   bsum  = (int*)wsp;   wsp += 256 * sizeof(int);
    unsigned* posd = (unsigned*)wsp; wsp += (size_t)E_TOT * sizeof(unsigned);
    unsigned short* csr_src = (unsigned short*)wsp;
    wsp += (size_t)E_TOT * sizeof(unsigned short);

    hipLaunchKernelGGL(k_gemm, dim3((N_NODES + BM - 1) / BM), dim3(256), 0, stream,
                       x, W, att_src, att_dst, h, a_src, a_dst, cnt);
    hipLaunchKernelGGL(k_count, dim3((E_TOT + 255) / 256), dim3(256), 0, stream,
                       ei, cnt, posd);
    hipLaunchKernelGGL(k_scan_block, dim3(SCAN_BLOCKS), dim3(256), 0, stream,
                       cnt, row, bsum);
    hipLaunchKernelGGL(k_scan_top_add, dim3(SCAN_BLOCKS), dim3(256), 0, stream,
                       row, bsum);
    hipLaunchKernelGGL(k_fill, dim3((E_TOT + 255) / 256), dim3(256), 0, stream,
                       ei, row, posd, csr_src);
    hipLaunchKernelGGL(k_node, dim3(((size_t)(N_NODES / 2) * 64 + 255) / 256), dim3(256),
                       0, stream, row, csr_src, a_src, a_dst, h, bias, out);
}